// Round 2
// baseline (291.436 us; speedup 1.0000x reference)
//
#include <hip/hip_runtime.h>
#include <hip/hip_bf16.h>

// B=16384 W=5 L=20 E=50 V=100000 C=128 H=4096 O=50
// ha   = bf16 [16384][256] (K: 250 data + [250]=1.0 bias + pad)  ws+0     (8 MB)
// wbf  = bf16 fc1 weights in MFMA A-frag layout:                 ws+8M    (2 MB)
//        frag f = CT*8 + ks (CT = n>>4, ks = k>>5); lane = q*16+m
//        short at (f*64 + lane)*8 + j  == wb[CT*16+m][ks*32+q*8+j]
// w2bf = bf16 fc2 weights in MFMA B-frag layout:                 ws+10M   (0.5 MB)
//        frag f = kst*4 + Ot; short at (f*64+lane)*8+j == w2b[Ot*16+m][kst*32+q*8+j]
// gt   = fp32 [128][156]                                         ws+11M   (78 KB)
// h (16384x4096) is NEVER materialized in HBM: fc1+tanh+fc2+softmax fused,
// h staged per-chunk (64x128) through 16KB of LDS in fc2-A-frag layout.
// NOTE: the fc1->fc2 LDS handoff is WAVE-PRIVATE (wave wv writes exactly the
// ks2l==wv frags and reads exactly the ks2l==wv frags), so the main loop
// needs NO __syncthreads(); only one barrier before the epilogue spill
// (part[] overlaps other waves' hs region).

typedef __attribute__((ext_vector_type(8))) short short8;
typedef __attribute__((ext_vector_type(4))) float float4v;

__device__ inline short bf16b(float f) {
    __hip_bfloat16 h = __float2bfloat16(f);
    return *reinterpret_cast<short*>(&h);
}
__device__ inline uint packbf2(float a, float b) {
    return (uint)(ushort)bf16b(a) | ((uint)(ushort)bf16b(b) << 16);
}

// ---------------------------------------------------------------------------
// fc1 weights + bias -> bf16, directly in MFMA fragment order.
__global__ void wbf_kernel(const float* __restrict__ fc1_w,
                           const float* __restrict__ fc1_b,
                           short* __restrict__ wbf) {
    int idx = blockIdx.x * 256 + threadIdx.x;     // n*256 + k
    int n = idx >> 8, k = idx & 255;
    float v = (k < 250) ? fc1_w[n * 250 + k] : (k == 250 ? fc1_b[n] : 0.f);
    int CT = n >> 4, mm = n & 15;
    int ks = k >> 5, qq = (k >> 3) & 3, j = k & 7;
    wbf[((CT * 8 + ks) * 64 + qq * 16 + mm) * 8 + j] = bf16b(v);
}

// ---------------------------------------------------------------------------
// fc2 weights (padded to 64 rows) -> bf16, in MFMA B-frag order.
__global__ void w2bf_kernel(const float* __restrict__ fc2_w,
                            short* __restrict__ w2bf) {
    int idx = blockIdx.x * 256 + threadIdx.x;     // o*4096 + k
    int o = idx >> 12, k = idx & 4095;
    float v = (o < 50) ? fc2_w[idx] : 0.f;
    int Ot = o >> 4, mm = o & 15;
    int kst = k >> 5, qq = (k >> 3) & 3, j = k & 7;
    w2bf[((kst * 4 + Ot) * 64 + qq * 16 + mm) * 8 + j] = bf16b(v);
}

// ---------------------------------------------------------------------------
__global__ void gt_kernel(const float* __restrict__ char_emb,
                          const float* __restrict__ conv_w,
                          float* __restrict__ gt) {
    int idx = blockIdx.x * 256 + threadIdx.x;     // < 19200
    if (idx >= 19200) return;
    int c = idx / 150, rem = idx - c * 150;
    int kk = rem / 50, o = rem - kk * 50;
    const float* ce = char_emb + c * 50;
    const float* w  = conv_w + o * 150 + kk;
    float s = 0.f;
    #pragma unroll 10
    for (int i = 0; i < 50; ++i) s += ce[i] * w[i * 3];
    gt[c * 156 + kk * 52 + o] = s;
}

// ---------------------------------------------------------------------------
__global__ void haPad_kernel(__hip_bfloat16* __restrict__ ha) {
    int idx = blockIdx.x * 256 + threadIdx.x;     // b*6 + j
    int b = idx / 6, j = idx - b * 6;
    ha[b * 256 + 250 + j] = __float2bfloat16(j == 0 ? 1.f : 0.f);
}

// ---------------------------------------------------------------------------
// conv via table lookup (unchanged, proven R7). Block = 512 thr = 32 words.
// ---------------------------------------------------------------------------
__global__ __launch_bounds__(512) void conv_kernel(
    const int* __restrict__ x, const int* __restrict__ wci,
    const float* __restrict__ word_emb, const float* __restrict__ conv_b,
    const float* __restrict__ gt, __hip_bfloat16* __restrict__ ha)
{
    __shared__ float Gs[19968];       // 79,872 B
    __shared__ uint  cpack[160];
    __shared__ int   xs[32];

    const int tid = threadIdx.x;
    const int gw0 = blockIdx.x * 32;

    int xr = 0;
    if (tid < 32) xr = x[gw0 + tid];

    #pragma unroll
    for (int t = 0; t < 39; ++t)
        Gs[t * 512 + tid] = gt[t * 512 + tid];

    if (tid < 32) {
        const int* crow = wci + xr * 20;
        int cid[20];
        #pragma unroll
        for (int p = 0; p < 20; ++p) cid[p] = crow[p];
        #pragma unroll
        for (int u = 0; u < 5; ++u)
            cpack[tid * 5 + u] = (uint)cid[u * 4] | ((uint)cid[u * 4 + 1] << 8)
                               | ((uint)cid[u * 4 + 2] << 16) | ((uint)cid[u * 4 + 3] << 24);
        xs[tid] = xr;
    }
    __syncthreads();

    const int lane = tid & 63;
    const int wv   = tid >> 6;
    const int t    = lane & 15;
    const int w    = lane >> 4;
    const int tc   = (t < 13) ? t : 12;
    const int widx = wv * 4 + w;

    uint cw[5];
    #pragma unroll
    for (int u = 0; u < 5; ++u) cw[u] = cpack[widx * 5 + u];
    int ca[20];
    #pragma unroll
    for (int p = 0; p < 20; ++p)
        ca[p] = (int)((cw[p >> 2] >> ((p & 3) * 8)) & 0xFF) * 156;

    const int tc4 = tc * 4;
    float4 mx;
    {
        float4 v = *(const float4*)&Gs[ca[0] + 52 + tc4];
        float4 u = *(const float4*)&Gs[ca[1] + 104 + tc4];
        mx.x = v.x + u.x; mx.y = v.y + u.y; mx.z = v.z + u.z; mx.w = v.w + u.w;
    }
    #pragma unroll
    for (int l = 1; l < 19; ++l) {
        float4 v = *(const float4*)&Gs[ca[l] + 52 + tc4];
        float4 a = *(const float4*)&Gs[ca[l - 1] + tc4];
        float4 b = *(const float4*)&Gs[ca[l + 1] + 104 + tc4];
        float vx = v.x + a.x + b.x, vy = v.y + a.y + b.y;
        float vz = v.z + a.z + b.z, vw = v.w + a.w + b.w;
        mx.x = fmaxf(mx.x, vx); mx.y = fmaxf(mx.y, vy);
        mx.z = fmaxf(mx.z, vz); mx.w = fmaxf(mx.w, vw);
    }
    {
        float4 v = *(const float4*)&Gs[ca[19] + 52 + tc4];
        float4 a = *(const float4*)&Gs[ca[18] + tc4];
        mx.x = fmaxf(mx.x, v.x + a.x); mx.y = fmaxf(mx.y, v.y + a.y);
        mx.z = fmaxf(mx.z, v.z + a.z); mx.w = fmaxf(mx.w, v.w + a.w);
    }

    const int xid = xs[widx];
    const float* wer = word_emb + (size_t)xid * 50 + tc4;
    float2 wea = *(const float2*)wer;
    float2 web = make_float2(0.f, 0.f);
    float2 cba = *(const float2*)(conv_b + tc4);
    float2 cbb = make_float2(0.f, 0.f);
    if (tc < 12) {
        web = *(const float2*)(wer + 2);
        cbb = *(const float2*)(conv_b + tc4 + 2);
    }
    const int gw = gw0 + widx, b = gw / 5, wp = gw - b * 5;
    __hip_bfloat16* dst = ha + b * 256 + wp * 50 + tc4;
    uint lo = packbf2(mx.x + cba.x + wea.x, mx.y + cba.y + wea.y);
    if (t < 12) {
        uint hi = packbf2(mx.z + cbb.x + web.x, mx.w + cbb.y + web.y);
        *(uint*)dst = lo;
        *((uint*)dst + 1) = hi;
    } else if (t == 12) {
        *(uint*)dst = lo;
    }
}

// ---------------------------------------------------------------------------
// Fused fc1 + tanh + fc2 + softmax. 256 blocks x 256 thr, 64 rows/block.
// - ha A-frags (64x256) loaded once into 128 VGPRs per lane.
// - fc1 B streams from wbf (frag layout, coalesced 16B/lane, L2-resident).
// - per 128-col h-chunk: MFMA (operand-swapped, D-rows = h-cols) -> tanh ->
//   pack to fc2-A-frag layout in 16KB LDS (proven R12-R14 algebra) ->
//   fc2 MFMA with K-split across the 4 waves, accumulated in regs across
//   all 32 chunks. Handoff is wave-private -> NO barriers in the main loop.
// ---------------------------------------------------------------------------
__global__ __launch_bounds__(256, 1) void fused_kernel(
    const __hip_bfloat16* __restrict__ ha, const short* __restrict__ wbf,
    const short* __restrict__ w2bf, const float* __restrict__ fc2_b,
    float* __restrict__ out)
{
    __shared__ float part[4][64][64];            // 64 KB; first 16KB alias hs
    short* hs = (short*)&part[0][0][0];          // 1024 short8 frags

    const int tid  = threadIdx.x;
    const int lane = tid & 63;
    const int wv   = tid >> 6;
    const int q = lane >> 4, m = lane & 15;
    const int m0 = blockIdx.x * 64;

    // ha A-fragments for this block's 64 rows, all K=256: 32 frags/lane.
    short8 av[4][8];
    #pragma unroll
    for (int mt = 0; mt < 4; ++mt)
        #pragma unroll
        for (int ks = 0; ks < 8; ++ks)
            av[mt][ks] = *(const short8*)(ha
                + (size_t)(m0 + mt * 16 + m) * 256 + ks * 32 + q * 8);

    float4v acc2[4][4] = {};    // fc2 accum: [row-tile][out-col-tile]

    for (int ch = 0; ch < 32; ++ch) {
        // ---- fc1: h-chunk cols [ch*128, ch*128+128); wave owns 32 cols ----
        float4v acc[4][2] = {};
        #pragma unroll
        for (int ks = 0; ks < 8; ++ks) {
            short8 bv[2];
            #pragma unroll
            for (int nt = 0; nt < 2; ++nt)
                bv[nt] = *(const short8*)(wbf
                    + ((size_t)((ch * 8 + wv * 2 + nt) * 8 + ks) * 64 + lane) * 8);
            #pragma unroll
            for (int mt = 0; mt < 4; ++mt)
                #pragma unroll
                for (int nt = 0; nt < 2; ++nt)
                    acc[mt][nt] = __builtin_amdgcn_mfma_f32_16x16x32_bf16(
                        bv[nt], av[mt][ks], acc[mt][nt], 0, 0, 0);
        }
        // ---- tanh + pack to fc2-A-frag layout in LDS (wave-private) ----
        const int q2base = q >> 1, slot = q & 1;
        #pragma unroll
        for (int mt = 0; mt < 4; ++mt) {
            #pragma unroll
            for (int nt = 0; nt < 2; ++nt) {
                float tv[4];
                #pragma unroll
                for (int r = 0; r < 4; ++r)
                    tv[r] = 1.f - 2.f / (__expf(2.f * acc[mt][nt][r]) + 1.f);
                const int CTl = wv * 2 + nt;           // local h-col tile 0..7
                const int ks2l = CTl >> 1;             // == wv (wave-private!)
                const int q2 = (CTl & 1) * 2 + q2base;
                const uint p0 = packbf2(tv[0], tv[1]);
                const uint p1 = packbf2(tv[2], tv[3]);
                *(uint2*)((char*)hs
                    + (((mt * 4 + ks2l) * 64 + q2 * 16 + m) * 16 + slot * 8))
                    = make_uint2(p0, p1);
            }
        }
        // ---- fc2 partial: wave wv takes local k-slice [wv*32, wv*32+32) ----
        // reads only ks2l==wv frags == its own writes; no barrier needed.
        {
            short8 a2[4], b2[4];
            #pragma unroll
            for (int Rl = 0; Rl < 4; ++Rl)
                a2[Rl] = *(const short8*)(hs + ((Rl * 4 + wv) * 64 + lane) * 8);
            const int kst = ch * 4 + wv;               // global k/32
            #pragma unroll
            for (int Ot = 0; Ot < 4; ++Ot)
                b2[Ot] = *(const short8*)(w2bf
                    + ((size_t)(kst * 4 + Ot) * 64 + lane) * 8);
            #pragma unroll
            for (int Rl = 0; Rl < 4; ++Rl)
                #pragma unroll
                for (int Ot = 0; Ot < 4; ++Ot)
                    acc2[Rl][Ot] = __builtin_amdgcn_mfma_f32_16x16x32_bf16(
                        a2[Rl], b2[Ot], acc2[Rl][Ot], 0, 0, 0);
        }
    }

    // all waves must be done with hs before part[] is written over it
    __syncthreads();

    // ---- epilogue: spill per-wave partials, reduce, bias, softmax ----
    #pragma unroll
    for (int Rl = 0; Rl < 4; ++Rl)
        #pragma unroll
        for (int Ot = 0; Ot < 4; ++Ot)
            #pragma unroll
            for (int r = 0; r < 4; ++r)
                part[wv][Rl * 16 + q * 4 + r][Ot * 16 + m] = acc2[Rl][Ot][r];
    __syncthreads();

    #pragma unroll
    for (int t = 0; t < 16; ++t) {
        int idx = t * 256 + tid;
        int row = idx >> 6, col = idx & 63;
        float lg = part[0][row][col] + part[1][row][col]
                 + part[2][row][col] + part[3][row][col];
        part[0][row][col] = (col < 50) ? lg + fc2_b[col] : -1e30f;
    }
    __syncthreads();

    #pragma unroll
    for (int rr = 0; rr < 16; ++rr) {
        const int row = wv * 16 + rr;
        float v = part[0][row][lane];
        float mx = v;
        #pragma unroll
        for (int off = 32; off > 0; off >>= 1) mx = fmaxf(mx, __shfl_xor(mx, off));
        float e = __expf(v - mx);
        float s = e;
        #pragma unroll
        for (int off = 32; off > 0; off >>= 1) s += __shfl_xor(s, off);
        if (lane < 50)
            out[(size_t)(m0 + row) * 50 + lane] = e / s;
    }
}

// ---------------------------------------------------------------------------
extern "C" void kernel_launch(void* const* d_in, const int* in_sizes, int n_in,
                              void* d_out, int out_size, void* d_ws, size_t ws_size,
                              hipStream_t stream) {
    const int*   x        = (const int*)  d_in[0];
    const int*   wci      = (const int*)  d_in[1];
    const float* word_emb = (const float*)d_in[2];
    const float* char_emb = (const float*)d_in[3];
    const float* conv_w   = (const float*)d_in[4];
    const float* conv_b   = (const float*)d_in[5];
    const float* fc1_w    = (const float*)d_in[6];
    const float* fc1_b    = (const float*)d_in[7];
    const float* fc2_w    = (const float*)d_in[8];
    const float* fc2_b    = (const float*)d_in[9];
    float* out = (float*)d_out;

    char* ws = (char*)d_ws;
    __hip_bfloat16* ha  = (__hip_bfloat16*)ws;                        // 8 MB
    short* wbf  = (short*)(ws + ((size_t)8  << 20));                  // 2 MB
    short* w2bf = (short*)(ws + ((size_t)10 << 20));                  // 0.5 MB
    float* gtp  = (float*)(ws + ((size_t)11 << 20));                  // 78 KB

    wbf_kernel<<<4096, 256, 0, stream>>>(fc1_w, fc1_b, wbf);
    w2bf_kernel<<<1024, 256, 0, stream>>>(fc2_w, w2bf);
    gt_kernel<<<75, 256, 0, stream>>>(char_emb, conv_w, gtp);
    haPad_kernel<<<384, 256, 0, stream>>>(ha);
    conv_kernel<<<2560, 512, 0, stream>>>(x, wci, word_emb, conv_b, gtp, ha);
    fused_kernel<<<256, 256, 0, stream>>>(ha, wbf, w2bf, fc2_b, out);
}

// Round 3
// 286.994 us; speedup vs baseline: 1.0155x; 1.0155x over previous
//
#include <hip/hip_runtime.h>
#include <hip/hip_bf16.h>

// B=16384 W=5 L=20 E=50 V=100000 C=128 H=4096 O=50
// ha   = bf16 [16384][256] (K: 250 data + [250]=1.0 bias + pad)  ws+0     (8 MB)
// wbf  = bf16 fc1 weights in MFMA A-frag layout:                 ws+8M    (2 MB)
//        frag f = CT*8 + ks (CT = n>>4, ks = k>>5); lane = q*16+m
//        short at (f*64 + lane)*8 + j  == wb[CT*16+m][ks*32+q*8+j]
// w2bf = bf16 fc2 weights in MFMA B-frag layout:                 ws+10M   (0.5 MB)
//        frag f = kst*4 + Ot; short at (f*64+lane)*8+j == w2b[Ot*16+m][kst*32+q*8+j]
// gt   = fp32 [128][156]                                         ws+11M   (78 KB)
// h (16384x4096) never hits HBM: fc1+tanh+fc2+softmax fused.
// R2 lesson: 64 rows/block needed ~230 live VGPRs -> compiler demoted the
// persistent ha frags (VGPR_Count=148) and 1 block/CU exposed every stall
// (Occ 11%, 164us). R3: 32 rows/block, 512 blocks -> ~150 VGPR fits,
// 2 blocks/CU = 2 waves/SIMD. Wave-private hs handoff (ks2l==wv) unchanged.

typedef __attribute__((ext_vector_type(8))) short short8;
typedef __attribute__((ext_vector_type(4))) float float4v;

__device__ inline short bf16b(float f) {
    __hip_bfloat16 h = __float2bfloat16(f);
    return *reinterpret_cast<short*>(&h);
}
__device__ inline uint packbf2(float a, float b) {
    return (uint)(ushort)bf16b(a) | ((uint)(ushort)bf16b(b) << 16);
}

// ---------------------------------------------------------------------------
// fc1 weights + bias -> bf16, directly in MFMA fragment order.
__global__ void wbf_kernel(const float* __restrict__ fc1_w,
                           const float* __restrict__ fc1_b,
                           short* __restrict__ wbf) {
    int idx = blockIdx.x * 256 + threadIdx.x;     // n*256 + k
    int n = idx >> 8, k = idx & 255;
    float v = (k < 250) ? fc1_w[n * 250 + k] : (k == 250 ? fc1_b[n] : 0.f);
    int CT = n >> 4, mm = n & 15;
    int ks = k >> 5, qq = (k >> 3) & 3, j = k & 7;
    wbf[((CT * 8 + ks) * 64 + qq * 16 + mm) * 8 + j] = bf16b(v);
}

// ---------------------------------------------------------------------------
// fc2 weights (padded to 64 rows) -> bf16, in MFMA B-frag order.
__global__ void w2bf_kernel(const float* __restrict__ fc2_w,
                            short* __restrict__ w2bf) {
    int idx = blockIdx.x * 256 + threadIdx.x;     // o*4096 + k
    int o = idx >> 12, k = idx & 4095;
    float v = (o < 50) ? fc2_w[idx] : 0.f;
    int Ot = o >> 4, mm = o & 15;
    int kst = k >> 5, qq = (k >> 3) & 3, j = k & 7;
    w2bf[((kst * 4 + Ot) * 64 + qq * 16 + mm) * 8 + j] = bf16b(v);
}

// ---------------------------------------------------------------------------
__global__ void gt_kernel(const float* __restrict__ char_emb,
                          const float* __restrict__ conv_w,
                          float* __restrict__ gt) {
    int idx = blockIdx.x * 256 + threadIdx.x;     // < 19200
    if (idx >= 19200) return;
    int c = idx / 150, rem = idx - c * 150;
    int kk = rem / 50, o = rem - kk * 50;
    const float* ce = char_emb + c * 50;
    const float* w  = conv_w + o * 150 + kk;
    float s = 0.f;
    #pragma unroll 10
    for (int i = 0; i < 50; ++i) s += ce[i] * w[i * 3];
    gt[c * 156 + kk * 52 + o] = s;
}

// ---------------------------------------------------------------------------
__global__ void haPad_kernel(__hip_bfloat16* __restrict__ ha) {
    int idx = blockIdx.x * 256 + threadIdx.x;     // b*6 + j
    int b = idx / 6, j = idx - b * 6;
    ha[b * 256 + 250 + j] = __float2bfloat16(j == 0 ? 1.f : 0.f);
}

// ---------------------------------------------------------------------------
// conv via table lookup (unchanged, proven R7). Block = 512 thr = 32 words.
// ---------------------------------------------------------------------------
__global__ __launch_bounds__(512) void conv_kernel(
    const int* __restrict__ x, const int* __restrict__ wci,
    const float* __restrict__ word_emb, const float* __restrict__ conv_b,
    const float* __restrict__ gt, __hip_bfloat16* __restrict__ ha)
{
    __shared__ float Gs[19968];       // 79,872 B
    __shared__ uint  cpack[160];
    __shared__ int   xs[32];

    const int tid = threadIdx.x;
    const int gw0 = blockIdx.x * 32;

    int xr = 0;
    if (tid < 32) xr = x[gw0 + tid];

    #pragma unroll
    for (int t = 0; t < 39; ++t)
        Gs[t * 512 + tid] = gt[t * 512 + tid];

    if (tid < 32) {
        const int* crow = wci + xr * 20;
        int cid[20];
        #pragma unroll
        for (int p = 0; p < 20; ++p) cid[p] = crow[p];
        #pragma unroll
        for (int u = 0; u < 5; ++u)
            cpack[tid * 5 + u] = (uint)cid[u * 4] | ((uint)cid[u * 4 + 1] << 8)
                               | ((uint)cid[u * 4 + 2] << 16) | ((uint)cid[u * 4 + 3] << 24);
        xs[tid] = xr;
    }
    __syncthreads();

    const int lane = tid & 63;
    const int wv   = tid >> 6;
    const int t    = lane & 15;
    const int w    = lane >> 4;
    const int tc   = (t < 13) ? t : 12;
    const int widx = wv * 4 + w;

    uint cw[5];
    #pragma unroll
    for (int u = 0; u < 5; ++u) cw[u] = cpack[widx * 5 + u];
    int ca[20];
    #pragma unroll
    for (int p = 0; p < 20; ++p)
        ca[p] = (int)((cw[p >> 2] >> ((p & 3) * 8)) & 0xFF) * 156;

    const int tc4 = tc * 4;
    float4 mx;
    {
        float4 v = *(const float4*)&Gs[ca[0] + 52 + tc4];
        float4 u = *(const float4*)&Gs[ca[1] + 104 + tc4];
        mx.x = v.x + u.x; mx.y = v.y + u.y; mx.z = v.z + u.z; mx.w = v.w + u.w;
    }
    #pragma unroll
    for (int l = 1; l < 19; ++l) {
        float4 v = *(const float4*)&Gs[ca[l] + 52 + tc4];
        float4 a = *(const float4*)&Gs[ca[l - 1] + tc4];
        float4 b = *(const float4*)&Gs[ca[l + 1] + 104 + tc4];
        float vx = v.x + a.x + b.x, vy = v.y + a.y + b.y;
        float vz = v.z + a.z + b.z, vw = v.w + a.w + b.w;
        mx.x = fmaxf(mx.x, vx); mx.y = fmaxf(mx.y, vy);
        mx.z = fmaxf(mx.z, vz); mx.w = fmaxf(mx.w, vw);
    }
    {
        float4 v = *(const float4*)&Gs[ca[19] + 52 + tc4];
        float4 a = *(const float4*)&Gs[ca[18] + tc4];
        mx.x = fmaxf(mx.x, v.x + a.x); mx.y = fmaxf(mx.y, v.y + a.y);
        mx.z = fmaxf(mx.z, v.z + a.z); mx.w = fmaxf(mx.w, v.w + a.w);
    }

    const int xid = xs[widx];
    const float* wer = word_emb + (size_t)xid * 50 + tc4;
    float2 wea = *(const float2*)wer;
    float2 web = make_float2(0.f, 0.f);
    float2 cba = *(const float2*)(conv_b + tc4);
    float2 cbb = make_float2(0.f, 0.f);
    if (tc < 12) {
        web = *(const float2*)(wer + 2);
        cbb = *(const float2*)(conv_b + tc4 + 2);
    }
    const int gw = gw0 + widx, b = gw / 5, wp = gw - b * 5;
    __hip_bfloat16* dst = ha + b * 256 + wp * 50 + tc4;
    uint lo = packbf2(mx.x + cba.x + wea.x, mx.y + cba.y + wea.y);
    if (t < 12) {
        uint hi = packbf2(mx.z + cbb.x + web.x, mx.w + cbb.y + web.y);
        *(uint*)dst = lo;
        *((uint*)dst + 1) = hi;
    } else if (t == 12) {
        *(uint*)dst = lo;
    }
}

// ---------------------------------------------------------------------------
// Fused fc1 + tanh + fc2 + softmax. 512 blocks x 256 thr, 32 rows/block.
// - ha A-frags (32x256) held in 64 VGPRs/lane for the whole kernel.
// - fc1 B streams from wbf (frag layout, coalesced 16B/lane, L2-resident).
// - per 128-col h-chunk: MFMA (operand-swapped, D-rows = h-cols) -> tanh ->
//   pack to fc2-A-frag layout in 8KB LDS (wave-private: ks2l==wv) ->
//   fc2 MFMA K-split across the 4 waves, accumulated in regs over 32 chunks.
//   No barriers in the main loop.
// ---------------------------------------------------------------------------
__global__ __launch_bounds__(256, 2) void fused_kernel(
    const __hip_bfloat16* __restrict__ ha, const short* __restrict__ wbf,
    const short* __restrict__ w2bf, const float* __restrict__ fc2_b,
    float* __restrict__ out)
{
    __shared__ float part[4][32][64];            // 32 KB; first 8KB alias hs
    short* hs = (short*)&part[0][0][0];          // 512 short8 frags

    const int tid  = threadIdx.x;
    const int lane = tid & 63;
    const int wv   = tid >> 6;
    const int q = lane >> 4, m = lane & 15;
    const int m0 = blockIdx.x * 32;

    // ha A-fragments for this block's 32 rows, all K=256: 16 frags/lane.
    short8 av[2][8];
    #pragma unroll
    for (int mt = 0; mt < 2; ++mt)
        #pragma unroll
        for (int ks = 0; ks < 8; ++ks)
            av[mt][ks] = *(const short8*)(ha
                + (size_t)(m0 + mt * 16 + m) * 256 + ks * 32 + q * 8);

    float4v acc2[2][4] = {};    // fc2 accum: [row-tile][out-col-tile]

    for (int ch = 0; ch < 32; ++ch) {
        // ---- fc1: h-chunk cols [ch*128, ch*128+128); wave owns 32 cols ----
        float4v acc[2][2] = {};
        #pragma unroll
        for (int ks = 0; ks < 8; ++ks) {
            short8 bv[2];
            #pragma unroll
            for (int nt = 0; nt < 2; ++nt)
                bv[nt] = *(const short8*)(wbf
                    + ((size_t)((ch * 8 + wv * 2 + nt) * 8 + ks) * 64 + lane) * 8);
            #pragma unroll
            for (int mt = 0; mt < 2; ++mt)
                #pragma unroll
                for (int nt = 0; nt < 2; ++nt)
                    acc[mt][nt] = __builtin_amdgcn_mfma_f32_16x16x32_bf16(
                        bv[nt], av[mt][ks], acc[mt][nt], 0, 0, 0);
        }
        // ---- tanh + pack to fc2-A-frag layout in LDS (wave-private) ----
        const int q2base = q >> 1, slot = q & 1;
        #pragma unroll
        for (int mt = 0; mt < 2; ++mt) {
            #pragma unroll
            for (int nt = 0; nt < 2; ++nt) {
                float tv[4];
                #pragma unroll
                for (int r = 0; r < 4; ++r)
                    tv[r] = 1.f - 2.f / (__expf(2.f * acc[mt][nt][r]) + 1.f);
                const int CTl = wv * 2 + nt;           // local h-col tile 0..7
                const int ks2l = CTl >> 1;             // == wv (wave-private!)
                const int q2 = (CTl & 1) * 2 + q2base;
                const uint p0 = packbf2(tv[0], tv[1]);
                const uint p1 = packbf2(tv[2], tv[3]);
                *(uint2*)((char*)hs
                    + (((mt * 4 + ks2l) * 64 + q2 * 16 + m) * 16 + slot * 8))
                    = make_uint2(p0, p1);
            }
        }
        // ---- fc2 partial: wave wv takes local k-slice [wv*32, wv*32+32) ----
        // reads only ks2l==wv frags == its own writes; no barrier needed.
        {
            short8 a2[2], b2[4];
            #pragma unroll
            for (int Rl = 0; Rl < 2; ++Rl)
                a2[Rl] = *(const short8*)(hs + ((Rl * 4 + wv) * 64 + lane) * 8);
            const int kst = ch * 4 + wv;               // global k/32
            #pragma unroll
            for (int Ot = 0; Ot < 4; ++Ot)
                b2[Ot] = *(const short8*)(w2bf
                    + ((size_t)(kst * 4 + Ot) * 64 + lane) * 8);
            #pragma unroll
            for (int Rl = 0; Rl < 2; ++Rl)
                #pragma unroll
                for (int Ot = 0; Ot < 4; ++Ot)
                    acc2[Rl][Ot] = __builtin_amdgcn_mfma_f32_16x16x32_bf16(
                        a2[Rl], b2[Ot], acc2[Rl][Ot], 0, 0, 0);
        }
    }

    // all waves must be done with hs before part[] is written over it
    __syncthreads();

    // ---- epilogue: spill per-wave partials, reduce, bias, softmax ----
    #pragma unroll
    for (int Rl = 0; Rl < 2; ++Rl)
        #pragma unroll
        for (int Ot = 0; Ot < 4; ++Ot)
            #pragma unroll
            for (int r = 0; r < 4; ++r)
                part[wv][Rl * 16 + q * 4 + r][Ot * 16 + m] = acc2[Rl][Ot][r];
    __syncthreads();

    #pragma unroll
    for (int t = 0; t < 8; ++t) {
        int idx = t * 256 + tid;
        int row = idx >> 6, col = idx & 63;
        float lg = part[0][row][col] + part[1][row][col]
                 + part[2][row][col] + part[3][row][col];
        part[0][row][col] = (col < 50) ? lg + fc2_b[col] : -1e30f;
    }
    __syncthreads();

    #pragma unroll
    for (int rr = 0; rr < 8; ++rr) {
        const int row = wv * 8 + rr;
        float v = part[0][row][lane];
        float mx = v;
        #pragma unroll
        for (int off = 32; off > 0; off >>= 1) mx = fmaxf(mx, __shfl_xor(mx, off));
        float e = __expf(v - mx);
        float s = e;
        #pragma unroll
        for (int off = 32; off > 0; off >>= 1) s += __shfl_xor(s, off);
        if (lane < 50)
            out[(size_t)(m0 + row) * 50 + lane] = e / s;
    }
}

// ---------------------------------------------------------------------------
extern "C" void kernel_launch(void* const* d_in, const int* in_sizes, int n_in,
                              void* d_out, int out_size, void* d_ws, size_t ws_size,
                              hipStream_t stream) {
    const int*   x        = (const int*)  d_in[0];
    const int*   wci      = (const int*)  d_in[1];
    const float* word_emb = (const float*)d_in[2];
    const float* char_emb = (const float*)d_in[3];
    const float* conv_w   = (const float*)d_in[4];
    const float* conv_b   = (const float*)d_in[5];
    const float* fc1_w    = (const float*)d_in[6];
    const float* fc1_b    = (const float*)d_in[7];
    const float* fc2_w    = (const float*)d_in[8];
    const float* fc2_b    = (const float*)d_in[9];
    float* out = (float*)d_out;

    char* ws = (char*)d_ws;
    __hip_bfloat16* ha  = (__hip_bfloat16*)ws;                        // 8 MB
    short* wbf  = (short*)(ws + ((size_t)8  << 20));                  // 2 MB
    short* w2bf = (short*)(ws + ((size_t)10 << 20));                  // 0.5 MB
    float* gtp  = (float*)(ws + ((size_t)11 << 20));                  // 78 KB

    wbf_kernel<<<4096, 256, 0, stream>>>(fc1_w, fc1_b, wbf);
    w2bf_kernel<<<1024, 256, 0, stream>>>(fc2_w, w2bf);
    gt_kernel<<<75, 256, 0, stream>>>(char_emb, conv_w, gtp);
    haPad_kernel<<<384, 256, 0, stream>>>(ha);
    conv_kernel<<<2560, 512, 0, stream>>>(x, wci, word_emb, conv_b, gtp, ha);
    fused_kernel<<<512, 256, 0, stream>>>(ha, wbf, w2bf, fc2_b, out);
}

// Round 4
// 222.289 us; speedup vs baseline: 1.3111x; 1.2911x over previous
//
#include <hip/hip_runtime.h>
#include <hip/hip_bf16.h>

// B=16384 W=5 L=20 E=50 V=100000 C=128 H=4096 O=50
// ha   = bf16 [16384][256] (K: 250 data + [250]=1.0 bias + pad)  ws+0     (8 MB)
// wbf  = bf16 fc1 weights in MFMA A-frag layout:                 ws+8M    (2 MB)
//        frag f = CT*8 + ks (CT = n>>4, ks = k>>5); lane = q*16+m
//        short at (f*64 + lane)*8 + j  == wb[CT*16+m][ks*32+q*8+j]
// w2bf = bf16 fc2 weights in MFMA B-frag layout:                 ws+10M   (0.5 MB)
//        frag f = kst*4 + Ot; short at (f*64+lane)*8+j == w2b[Ot*16+m][kst*32+q*8+j]
// gt   = fp32 [128][156]                                         ws+11M   (78 KB)
// h (16384x4096) never hits HBM.
// R3 post-mortem: fused kernel was L2-BW-bound (av reloads + per-wave bv reg
// loads = 288KB/chunk/CU ~ 5.1k cyc/chunk) with exposed latency (VGPR=72).
// R4: 64 rows/block (halves weight re-reads to 640MB total), B chunk staged
// in LDS via reg-prefetch (T14 async split), A held in regs (32 rows/wave =
// 64 VGPR only), 2 barriers/chunk m97-style.

typedef __attribute__((ext_vector_type(8))) short short8;
typedef __attribute__((ext_vector_type(4))) float float4v;

__device__ inline short bf16b(float f) {
    __hip_bfloat16 h = __float2bfloat16(f);
    return *reinterpret_cast<short*>(&h);
}
__device__ inline uint packbf2(float a, float b) {
    return (uint)(ushort)bf16b(a) | ((uint)(ushort)bf16b(b) << 16);
}

// ---------------------------------------------------------------------------
// fc1 weights + bias -> bf16, directly in MFMA fragment order.
__global__ void wbf_kernel(const float* __restrict__ fc1_w,
                           const float* __restrict__ fc1_b,
                           short* __restrict__ wbf) {
    int idx = blockIdx.x * 256 + threadIdx.x;     // n*256 + k
    int n = idx >> 8, k = idx & 255;
    float v = (k < 250) ? fc1_w[n * 250 + k] : (k == 250 ? fc1_b[n] : 0.f);
    int CT = n >> 4, mm = n & 15;
    int ks = k >> 5, qq = (k >> 3) & 3, j = k & 7;
    wbf[((CT * 8 + ks) * 64 + qq * 16 + mm) * 8 + j] = bf16b(v);
}

// ---------------------------------------------------------------------------
// fc2 weights (padded to 64 rows) -> bf16, in MFMA B-frag order.
__global__ void w2bf_kernel(const float* __restrict__ fc2_w,
                            short* __restrict__ w2bf) {
    int idx = blockIdx.x * 256 + threadIdx.x;     // o*4096 + k
    int o = idx >> 12, k = idx & 4095;
    float v = (o < 50) ? fc2_w[idx] : 0.f;
    int Ot = o >> 4, mm = o & 15;
    int kst = k >> 5, qq = (k >> 3) & 3, j = k & 7;
    w2bf[((kst * 4 + Ot) * 64 + qq * 16 + mm) * 8 + j] = bf16b(v);
}

// ---------------------------------------------------------------------------
__global__ void gt_kernel(const float* __restrict__ char_emb,
                          const float* __restrict__ conv_w,
                          float* __restrict__ gt) {
    int idx = blockIdx.x * 256 + threadIdx.x;     // < 19200
    if (idx >= 19200) return;
    int c = idx / 150, rem = idx - c * 150;
    int kk = rem / 50, o = rem - kk * 50;
    const float* ce = char_emb + c * 50;
    const float* w  = conv_w + o * 150 + kk;
    float s = 0.f;
    #pragma unroll 10
    for (int i = 0; i < 50; ++i) s += ce[i] * w[i * 3];
    gt[c * 156 + kk * 52 + o] = s;
}

// ---------------------------------------------------------------------------
__global__ void haPad_kernel(__hip_bfloat16* __restrict__ ha) {
    int idx = blockIdx.x * 256 + threadIdx.x;     // b*6 + j
    int b = idx / 6, j = idx - b * 6;
    ha[b * 256 + 250 + j] = __float2bfloat16(j == 0 ? 1.f : 0.f);
}

// ---------------------------------------------------------------------------
// conv via table lookup (unchanged, proven R7). Block = 512 thr = 32 words.
// ---------------------------------------------------------------------------
__global__ __launch_bounds__(512) void conv_kernel(
    const int* __restrict__ x, const int* __restrict__ wci,
    const float* __restrict__ word_emb, const float* __restrict__ conv_b,
    const float* __restrict__ gt, __hip_bfloat16* __restrict__ ha)
{
    __shared__ float Gs[19968];       // 79,872 B
    __shared__ uint  cpack[160];
    __shared__ int   xs[32];

    const int tid = threadIdx.x;
    const int gw0 = blockIdx.x * 32;

    int xr = 0;
    if (tid < 32) xr = x[gw0 + tid];

    #pragma unroll
    for (int t = 0; t < 39; ++t)
        Gs[t * 512 + tid] = gt[t * 512 + tid];

    if (tid < 32) {
        const int* crow = wci + xr * 20;
        int cid[20];
        #pragma unroll
        for (int p = 0; p < 20; ++p) cid[p] = crow[p];
        #pragma unroll
        for (int u = 0; u < 5; ++u)
            cpack[tid * 5 + u] = (uint)cid[u * 4] | ((uint)cid[u * 4 + 1] << 8)
                               | ((uint)cid[u * 4 + 2] << 16) | ((uint)cid[u * 4 + 3] << 24);
        xs[tid] = xr;
    }
    __syncthreads();

    const int lane = tid & 63;
    const int wv   = tid >> 6;
    const int t    = lane & 15;
    const int w    = lane >> 4;
    const int tc   = (t < 13) ? t : 12;
    const int widx = wv * 4 + w;

    uint cw[5];
    #pragma unroll
    for (int u = 0; u < 5; ++u) cw[u] = cpack[widx * 5 + u];
    int ca[20];
    #pragma unroll
    for (int p = 0; p < 20; ++p)
        ca[p] = (int)((cw[p >> 2] >> ((p & 3) * 8)) & 0xFF) * 156;

    const int tc4 = tc * 4;
    float4 mx;
    {
        float4 v = *(const float4*)&Gs[ca[0] + 52 + tc4];
        float4 u = *(const float4*)&Gs[ca[1] + 104 + tc4];
        mx.x = v.x + u.x; mx.y = v.y + u.y; mx.z = v.z + u.z; mx.w = v.w + u.w;
    }
    #pragma unroll
    for (int l = 1; l < 19; ++l) {
        float4 v = *(const float4*)&Gs[ca[l] + 52 + tc4];
        float4 a = *(const float4*)&Gs[ca[l - 1] + tc4];
        float4 b = *(const float4*)&Gs[ca[l + 1] + 104 + tc4];
        float vx = v.x + a.x + b.x, vy = v.y + a.y + b.y;
        float vz = v.z + a.z + b.z, vw = v.w + a.w + b.w;
        mx.x = fmaxf(mx.x, vx); mx.y = fmaxf(mx.y, vy);
        mx.z = fmaxf(mx.z, vz); mx.w = fmaxf(mx.w, vw);
    }
    {
        float4 v = *(const float4*)&Gs[ca[19] + 52 + tc4];
        float4 a = *(const float4*)&Gs[ca[18] + tc4];
        mx.x = fmaxf(mx.x, v.x + a.x); mx.y = fmaxf(mx.y, v.y + a.y);
        mx.z = fmaxf(mx.z, v.z + a.z); mx.w = fmaxf(mx.w, v.w + a.w);
    }

    const int xid = xs[widx];
    const float* wer = word_emb + (size_t)xid * 50 + tc4;
    float2 wea = *(const float2*)wer;
    float2 web = make_float2(0.f, 0.f);
    float2 cba = *(const float2*)(conv_b + tc4);
    float2 cbb = make_float2(0.f, 0.f);
    if (tc < 12) {
        web = *(const float2*)(wer + 2);
        cbb = *(const float2*)(conv_b + tc4 + 2);
    }
    const int gw = gw0 + widx, b = gw / 5, wp = gw - b * 5;
    __hip_bfloat16* dst = ha + b * 256 + wp * 50 + tc4;
    uint lo = packbf2(mx.x + cba.x + wea.x, mx.y + cba.y + wea.y);
    if (t < 12) {
        uint hi = packbf2(mx.z + cbb.x + web.x, mx.w + cbb.y + web.y);
        *(uint*)dst = lo;
        *((uint*)dst + 1) = hi;
    } else if (t == 12) {
        *(uint*)dst = lo;
    }
}

// ---------------------------------------------------------------------------
// Fused fc1 + tanh + fc2 + softmax. 256 blocks x 512 thr, 64 rows/block.
// Wave grid 2x4: wm = wv>>2 (row half), wn = wv&3 (col quarter / k-slice).
// LDS: Bs 64KB (wbf chunk) + hs 16KB; part[4][64][64] (64KB) aliases Bs.
// Per chunk: fc1 (A regs x Bs LDS) -> tanh -> hs -> barrier -> fc2 (hs + b2
// regs, 4-way K-split by wn) -> write prefetched B(ch+1) regs to Bs -> barrier.
// ---------------------------------------------------------------------------
__global__ __launch_bounds__(512, 2) void fused_kernel(
    const __hip_bfloat16* __restrict__ ha, const short* __restrict__ wbf,
    const short* __restrict__ w2bf, const float* __restrict__ fc2_b,
    float* __restrict__ out)
{
    __shared__ char smem[81920];                 // 80 KB
    short8* Bsv = (short8*)smem;                 // 4096 frags, 64 KB
    char*   hsb = smem + 65536;                  // 16 KB
    float*  partf = (float*)smem;                // [4][64][64] epilogue alias

    const int tid  = threadIdx.x;
    const int lane = tid & 63;
    const int wv   = tid >> 6;
    const int wm = wv >> 2, wn = wv & 3;
    const int q = lane >> 4, m = lane & 15;
    const int m0 = blockIdx.x * 64;

    const short8* wbfv  = (const short8*)wbf;    // frag-linear view
    const short8* w2bfv = (const short8*)w2bf;
    const short8* hav   = (const short8*)ha;

    // ---- A-frags: this wave's 32 rows, all K=256: 16 frags = 64 VGPR ----
    short8 av[2][8];
    #pragma unroll
    for (int mt = 0; mt < 2; ++mt)
        #pragma unroll
        for (int ks = 0; ks < 8; ++ks)
            av[mt][ks] = hav[(size_t)(m0 + wm * 32 + mt * 16 + m) * 32 + ks * 4 + q];

    // ---- prologue: stage B(0) into Bs (reg round-trip, batched) ----
    {
        short8 st[8];
        #pragma unroll
        for (int i = 0; i < 8; ++i) st[i] = wbfv[i * 512 + tid];
        #pragma unroll
        for (int i = 0; i < 8; ++i) Bsv[i * 512 + tid] = st[i];
    }
    __syncthreads();

    float4v acc2[4][2] = {};    // fc2 accum: [row-tile][out-col-pair], k=wn

    for (int ch = 0; ch < 32; ++ch) {
        // b2 frags for this chunk (used after fc1 -> latency hidden)
        short8 b2[2];
        #pragma unroll
        for (int Otp = 0; Otp < 2; ++Otp)
            b2[Otp] = w2bfv[(size_t)((ch * 4 + wn) * 4 + wm * 2 + Otp) * 64 + lane];

        // prefetch B(ch+1) into regs (T14: issue early, write late)
        short8 Bn[8];
        if (ch < 31) {
            #pragma unroll
            for (int i = 0; i < 8; ++i)
                Bn[i] = wbfv[(size_t)(ch + 1) * 4096 + i * 512 + tid];
        }

        // ---- fc1: rows [wm*32,+32) x cols [ch*128 + wn*32, +32) ----
        float4v acc[2][2] = {};
        #pragma unroll
        for (int ks = 0; ks < 8; ++ks) {
            short8 bv[2];
            #pragma unroll
            for (int nt = 0; nt < 2; ++nt)
                bv[nt] = Bsv[((wn * 2 + nt) * 8 + ks) * 64 + lane];
            #pragma unroll
            for (int mt = 0; mt < 2; ++mt)
                #pragma unroll
                for (int nt = 0; nt < 2; ++nt)
                    acc[mt][nt] = __builtin_amdgcn_mfma_f32_16x16x32_bf16(
                        bv[nt], av[mt][ks], acc[mt][nt], 0, 0, 0);
        }

        // ---- tanh + pack to fc2-A-frag layout in hs ----
        const int q2base = q >> 1, slot = q & 1;
        #pragma unroll
        for (int mt = 0; mt < 2; ++mt) {
            const int Rl = wm * 2 + mt;              // local row-tile 0..3
            #pragma unroll
            for (int nt = 0; nt < 2; ++nt) {
                float tv[4];
                #pragma unroll
                for (int r = 0; r < 4; ++r)
                    tv[r] = 1.f - 2.f / (__expf(2.f * acc[mt][nt][r]) + 1.f);
                const int q2 = nt * 2 + q2base;      // (CTl&1)*2 + q2base
                const uint p0 = packbf2(tv[0], tv[1]);
                const uint p1 = packbf2(tv[2], tv[3]);
                *(uint2*)(hsb + (((Rl * 4 + wn) * 64 + q2 * 16 + m) * 16 + slot * 8))
                    = make_uint2(p0, p1);
            }
        }
        __syncthreads();    // hs ready; all Bs reads for ch complete

        // ---- fc2 partial: wave's k-slice = [ch*128 + wn*32, +32) ----
        {
            short8 a2[4];
            #pragma unroll
            for (int Rl = 0; Rl < 4; ++Rl)
                a2[Rl] = *(const short8*)(hsb + ((Rl * 4 + wn) * 64 + lane) * 16);
            #pragma unroll
            for (int Rl = 0; Rl < 4; ++Rl)
                #pragma unroll
                for (int Otp = 0; Otp < 2; ++Otp)
                    acc2[Rl][Otp] = __builtin_amdgcn_mfma_f32_16x16x32_bf16(
                        a2[Rl], b2[Otp], acc2[Rl][Otp], 0, 0, 0);
        }

        // ---- write prefetched B(ch+1) into Bs ----
        if (ch < 31) {
            #pragma unroll
            for (int i = 0; i < 8; ++i) Bsv[i * 512 + tid] = Bn[i];
        }
        __syncthreads();    // Bs(ch+1) ready; hs free for rewrite
    }

    // ---- epilogue: spill k-partials, reduce, bias, softmax ----
    // (Bs region is dead; partf[4][64][64] aliases it)
    #pragma unroll
    for (int Rl = 0; Rl < 4; ++Rl)
        #pragma unroll
        for (int Otp = 0; Otp < 2; ++Otp)
            #pragma unroll
            for (int r = 0; r < 4; ++r)
                partf[(wn * 64 + Rl * 16 + q * 4 + r) * 64
                      + wm * 32 + Otp * 16 + m] = acc2[Rl][Otp][r];
    __syncthreads();

    #pragma unroll
    for (int t = 0; t < 8; ++t) {
        int idx = t * 512 + tid;
        int row = idx >> 6, col = idx & 63;
        float lg = partf[row * 64 + col] + partf[(64 + row) * 64 + col]
                 + partf[(128 + row) * 64 + col] + partf[(192 + row) * 64 + col];
        partf[row * 64 + col] = (col < 50) ? lg + fc2_b[col] : -1e30f;
    }
    __syncthreads();

    #pragma unroll
    for (int rr = 0; rr < 8; ++rr) {
        const int row = wv * 8 + rr;
        float v = partf[row * 64 + lane];
        float mx = v;
        #pragma unroll
        for (int off = 32; off > 0; off >>= 1) mx = fmaxf(mx, __shfl_xor(mx, off));
        float e = __expf(v - mx);
        float s = e;
        #pragma unroll
        for (int off = 32; off > 0; off >>= 1) s += __shfl_xor(s, off);
        if (lane < 50)
            out[(size_t)(m0 + row) * 50 + lane] = e / s;
    }
}

// ---------------------------------------------------------------------------
extern "C" void kernel_launch(void* const* d_in, const int* in_sizes, int n_in,
                              void* d_out, int out_size, void* d_ws, size_t ws_size,
                              hipStream_t stream) {
    const int*   x        = (const int*)  d_in[0];
    const int*   wci      = (const int*)  d_in[1];
    const float* word_emb = (const float*)d_in[2];
    const float* char_emb = (const float*)d_in[3];
    const float* conv_w   = (const float*)d_in[4];
    const float* conv_b   = (const float*)d_in[5];
    const float* fc1_w    = (const float*)d_in[6];
    const float* fc1_b    = (const float*)d_in[7];
    const float* fc2_w    = (const float*)d_in[8];
    const float* fc2_b    = (const float*)d_in[9];
    float* out = (float*)d_out;

    char* ws = (char*)d_ws;
    __hip_bfloat16* ha  = (__hip_bfloat16*)ws;                        // 8 MB
    short* wbf  = (short*)(ws + ((size_t)8  << 20));                  // 2 MB
    short* w2bf = (short*)(ws + ((size_t)10 << 20));                  // 0.5 MB
    float* gtp  = (float*)(ws + ((size_t)11 << 20));                  // 78 KB

    wbf_kernel<<<4096, 256, 0, stream>>>(fc1_w, fc1_b, wbf);
    w2bf_kernel<<<1024, 256, 0, stream>>>(fc2_w, w2bf);
    gt_kernel<<<75, 256, 0, stream>>>(char_emb, conv_w, gtp);
    haPad_kernel<<<384, 256, 0, stream>>>(ha);
    conv_kernel<<<2560, 512, 0, stream>>>(x, wci, word_emb, conv_b, gtp, ha);
    fused_kernel<<<256, 512, 0, stream>>>(ha, wbf, w2bf, fc2_b, out);
}

// Round 5
// 210.963 us; speedup vs baseline: 1.3815x; 1.0537x over previous
//
#include <hip/hip_runtime.h>
#include <hip/hip_bf16.h>

// B=16384 W=5 L=20 E=50 V=100000 C=128 H=4096 O=50
// ha   = bf16 [16384][256] (K: 250 data + [250]=1.0 bias + pad)  ws+0     (8 MB)
// wbf  = bf16 fc1 weights in MFMA A-frag layout:                 ws+8M    (2 MB)
//        frag f = CT*8 + ks (CT = n>>4, ks = k>>5); lane = q*16+m
//        short at (f*64 + lane)*8 + j  == wb[CT*16+m][ks*32+q*8+j]
// w2bf = bf16 fc2 weights in MFMA B-frag layout:                 ws+10M   (0.5 MB)
//        frag f = kst*4 + Ot; short at (f*64+lane)*8+j == w2b[Ot*16+m][kst*32+q*8+j]
// gt   = fp32 [128][156]                                         ws+11M   (78 KB)
// h (16384x4096) never hits HBM.
// R4 post-mortem: launch_bounds(512,2) capped VGPR at 128; together with the
// 64-reg Bn prefetch the allocator demoted av[2][8] (VGPR_Count=84) -> A
// re-fetched from L2 every chunk (~2100 cyc) on top of ~2000 cyc LDS.
// R5: (1) launch_bounds(512,1) -> cap 256; (2) av pinned via empty inline asm
// (defeats remat, the failure mode of R2/R3/R4); (3) B staged with
// global_load_lds width=16 into double-buffered Bs (frees 64 VGPR, async);
// mid-chunk raw s_barrier + lgkmcnt(0) only (prefetch stays in flight),
// end-of-chunk __syncthreads() supplies the vmcnt(0) drain.

typedef __attribute__((ext_vector_type(8))) short short8;
typedef __attribute__((ext_vector_type(4))) float float4v;

__device__ inline short bf16b(float f) {
    __hip_bfloat16 h = __float2bfloat16(f);
    return *reinterpret_cast<short*>(&h);
}
__device__ inline uint packbf2(float a, float b) {
    return (uint)(ushort)bf16b(a) | ((uint)(ushort)bf16b(b) << 16);
}
__device__ inline void gload_lds16(const void* g, void* l) {
    __builtin_amdgcn_global_load_lds(
        (const __attribute__((address_space(1))) unsigned int*)g,
        (__attribute__((address_space(3))) unsigned int*)l, 16, 0, 0);
}

// ---------------------------------------------------------------------------
// fc1 weights + bias -> bf16, directly in MFMA fragment order.
__global__ void wbf_kernel(const float* __restrict__ fc1_w,
                           const float* __restrict__ fc1_b,
                           short* __restrict__ wbf) {
    int idx = blockIdx.x * 256 + threadIdx.x;     // n*256 + k
    int n = idx >> 8, k = idx & 255;
    float v = (k < 250) ? fc1_w[n * 250 + k] : (k == 250 ? fc1_b[n] : 0.f);
    int CT = n >> 4, mm = n & 15;
    int ks = k >> 5, qq = (k >> 3) & 3, j = k & 7;
    wbf[((CT * 8 + ks) * 64 + qq * 16 + mm) * 8 + j] = bf16b(v);
}

// ---------------------------------------------------------------------------
// fc2 weights (padded to 64 rows) -> bf16, in MFMA B-frag order.
__global__ void w2bf_kernel(const float* __restrict__ fc2_w,
                            short* __restrict__ w2bf) {
    int idx = blockIdx.x * 256 + threadIdx.x;     // o*4096 + k
    int o = idx >> 12, k = idx & 4095;
    float v = (o < 50) ? fc2_w[idx] : 0.f;
    int Ot = o >> 4, mm = o & 15;
    int kst = k >> 5, qq = (k >> 3) & 3, j = k & 7;
    w2bf[((kst * 4 + Ot) * 64 + qq * 16 + mm) * 8 + j] = bf16b(v);
}

// ---------------------------------------------------------------------------
__global__ void gt_kernel(const float* __restrict__ char_emb,
                          const float* __restrict__ conv_w,
                          float* __restrict__ gt) {
    int idx = blockIdx.x * 256 + threadIdx.x;     // < 19200
    if (idx >= 19200) return;
    int c = idx / 150, rem = idx - c * 150;
    int kk = rem / 50, o = rem - kk * 50;
    const float* ce = char_emb + c * 50;
    const float* w  = conv_w + o * 150 + kk;
    float s = 0.f;
    #pragma unroll 10
    for (int i = 0; i < 50; ++i) s += ce[i] * w[i * 3];
    gt[c * 156 + kk * 52 + o] = s;
}

// ---------------------------------------------------------------------------
__global__ void haPad_kernel(__hip_bfloat16* __restrict__ ha) {
    int idx = blockIdx.x * 256 + threadIdx.x;     // b*6 + j
    int b = idx / 6, j = idx - b * 6;
    ha[b * 256 + 250 + j] = __float2bfloat16(j == 0 ? 1.f : 0.f);
}

// ---------------------------------------------------------------------------
// conv via table lookup (unchanged, proven R7). Block = 512 thr = 32 words.
// ---------------------------------------------------------------------------
__global__ __launch_bounds__(512) void conv_kernel(
    const int* __restrict__ x, const int* __restrict__ wci,
    const float* __restrict__ word_emb, const float* __restrict__ conv_b,
    const float* __restrict__ gt, __hip_bfloat16* __restrict__ ha)
{
    __shared__ float Gs[19968];       // 79,872 B
    __shared__ uint  cpack[160];
    __shared__ int   xs[32];

    const int tid = threadIdx.x;
    const int gw0 = blockIdx.x * 32;

    int xr = 0;
    if (tid < 32) xr = x[gw0 + tid];

    #pragma unroll
    for (int t = 0; t < 39; ++t)
        Gs[t * 512 + tid] = gt[t * 512 + tid];

    if (tid < 32) {
        const int* crow = wci + xr * 20;
        int cid[20];
        #pragma unroll
        for (int p = 0; p < 20; ++p) cid[p] = crow[p];
        #pragma unroll
        for (int u = 0; u < 5; ++u)
            cpack[tid * 5 + u] = (uint)cid[u * 4] | ((uint)cid[u * 4 + 1] << 8)
                               | ((uint)cid[u * 4 + 2] << 16) | ((uint)cid[u * 4 + 3] << 24);
        xs[tid] = xr;
    }
    __syncthreads();

    const int lane = tid & 63;
    const int wv   = tid >> 6;
    const int t    = lane & 15;
    const int w    = lane >> 4;
    const int tc   = (t < 13) ? t : 12;
    const int widx = wv * 4 + w;

    uint cw[5];
    #pragma unroll
    for (int u = 0; u < 5; ++u) cw[u] = cpack[widx * 5 + u];
    int ca[20];
    #pragma unroll
    for (int p = 0; p < 20; ++p)
        ca[p] = (int)((cw[p >> 2] >> ((p & 3) * 8)) & 0xFF) * 156;

    const int tc4 = tc * 4;
    float4 mx;
    {
        float4 v = *(const float4*)&Gs[ca[0] + 52 + tc4];
        float4 u = *(const float4*)&Gs[ca[1] + 104 + tc4];
        mx.x = v.x + u.x; mx.y = v.y + u.y; mx.z = v.z + u.z; mx.w = v.w + u.w;
    }
    #pragma unroll
    for (int l = 1; l < 19; ++l) {
        float4 v = *(const float4*)&Gs[ca[l] + 52 + tc4];
        float4 a = *(const float4*)&Gs[ca[l - 1] + tc4];
        float4 b = *(const float4*)&Gs[ca[l + 1] + 104 + tc4];
        float vx = v.x + a.x + b.x, vy = v.y + a.y + b.y;
        float vz = v.z + a.z + b.z, vw = v.w + a.w + b.w;
        mx.x = fmaxf(mx.x, vx); mx.y = fmaxf(mx.y, vy);
        mx.z = fmaxf(mx.z, vz); mx.w = fmaxf(mx.w, vw);
    }
    {
        float4 v = *(const float4*)&Gs[ca[19] + 52 + tc4];
        float4 a = *(const float4*)&Gs[ca[18] + tc4];
        mx.x = fmaxf(mx.x, v.x + a.x); mx.y = fmaxf(mx.y, v.y + a.y);
        mx.z = fmaxf(mx.z, v.z + a.z); mx.w = fmaxf(mx.w, v.w + a.w);
    }

    const int xid = xs[widx];
    const float* wer = word_emb + (size_t)xid * 50 + tc4;
    float2 wea = *(const float2*)wer;
    float2 web = make_float2(0.f, 0.f);
    float2 cba = *(const float2*)(conv_b + tc4);
    float2 cbb = make_float2(0.f, 0.f);
    if (tc < 12) {
        web = *(const float2*)(wer + 2);
        cbb = *(const float2*)(conv_b + tc4 + 2);
    }
    const int gw = gw0 + widx, b = gw / 5, wp = gw - b * 5;
    __hip_bfloat16* dst = ha + b * 256 + wp * 50 + tc4;
    uint lo = packbf2(mx.x + cba.x + wea.x, mx.y + cba.y + wea.y);
    if (t < 12) {
        uint hi = packbf2(mx.z + cbb.x + web.x, mx.w + cbb.y + web.y);
        *(uint*)dst = lo;
        *((uint*)dst + 1) = hi;
    } else if (t == 12) {
        *(uint*)dst = lo;
    }
}

// ---------------------------------------------------------------------------
// Fused fc1 + tanh + fc2 + softmax. 256 blocks x 512 thr, 64 rows/block.
// Wave grid 2x4: wm = wv>>2 (row half), wn = wv&3 (col quarter / k-slice).
// LDS: Bs double-buffer 2x64KB (global_load_lds staged) + hs 16KB = 144KB;
// part[4][64][64] (64KB) aliases Bs in the epilogue.
// Per chunk: [issue gload_lds B(ch+1) -> Bs[buf^1]] ; fc1 (A regs x Bs[buf])
// -> tanh -> hs ; raw s_barrier (lgkmcnt only; prefetch stays in flight) ;
// fc2 (hs + b2 regs, 4-way K-split by wn) ; __syncthreads() (vmcnt drain).
// ---------------------------------------------------------------------------
__global__ __launch_bounds__(512, 1) void fused_kernel(
    const __hip_bfloat16* __restrict__ ha, const short* __restrict__ wbf,
    const short* __restrict__ w2bf, const float* __restrict__ fc2_b,
    float* __restrict__ out)
{
    __shared__ char smem[147456];                // 144 KB
    short8* Bsv = (short8*)smem;                 // [2][4096] frags
    char*   hsb = smem + 131072;                 // 16 KB
    float*  partf = (float*)smem;                // [4][64][64] epilogue alias

    const int tid  = threadIdx.x;
    const int lane = tid & 63;
    const int wv   = tid >> 6;
    const int wm = wv >> 2, wn = wv & 3;
    const int q = lane >> 4, m = lane & 15;
    const int m0 = blockIdx.x * 64;
    const int wt = wv * 64;                      // wave-uniform thread base

    const short8* wbfv  = (const short8*)wbf;    // frag-linear view
    const short8* w2bfv = (const short8*)w2bf;
    const short8* hav   = (const short8*)ha;

    // ---- A-frags: this wave's 32 rows, all K=256: 16 frags = 64 VGPR ----
    short8 av[2][8];
    #pragma unroll
    for (int mt = 0; mt < 2; ++mt)
        #pragma unroll
        for (int ks = 0; ks < 8; ++ks)
            av[mt][ks] = hav[(size_t)(m0 + wm * 32 + mt * 16 + m) * 32 + ks * 4 + q];
    // pin: values become asm-opaque -> allocator cannot rematerialize the loads
    #pragma unroll
    for (int mt = 0; mt < 2; ++mt)
        #pragma unroll
        for (int ks = 0; ks < 8; ++ks)
            asm volatile("" : "+v"(av[mt][ks]));

    // ---- prologue: stage B(0) into Bs[0] via async direct-to-LDS ----
    #pragma unroll
    for (int i = 0; i < 8; ++i)
        gload_lds16(wbfv + i * 512 + tid, Bsv + i * 512 + wt);
    __syncthreads();                             // drains vmcnt -> Bs[0] ready

    float4v acc2[4][2] = {};    // fc2 accum: [row-tile][out-col-pair], k=wn

    for (int ch = 0; ch < 32; ++ch) {
        const int buf = ch & 1;

        // b2 frags for this chunk (oldest vmem ops -> waited without draining
        // the prefetch behind them)
        short8 b2[2];
        #pragma unroll
        for (int Otp = 0; Otp < 2; ++Otp)
            b2[Otp] = w2bfv[(size_t)((ch * 4 + wn) * 4 + wm * 2 + Otp) * 64 + lane];

        // async prefetch B(ch+1) into the other buffer (in flight until the
        // end-of-chunk __syncthreads)
        if (ch < 31) {
            #pragma unroll
            for (int i = 0; i < 8; ++i)
                gload_lds16(wbfv + (size_t)(ch + 1) * 4096 + i * 512 + tid,
                            Bsv + (buf ^ 1) * 4096 + i * 512 + wt);
        }

        // ---- fc1: rows [wm*32,+32) x cols [ch*128 + wn*32, +32) ----
        float4v acc[2][2] = {};
        #pragma unroll
        for (int ks = 0; ks < 8; ++ks) {
            short8 bv[2];
            #pragma unroll
            for (int nt = 0; nt < 2; ++nt)
                bv[nt] = Bsv[buf * 4096 + ((wn * 2 + nt) * 8 + ks) * 64 + lane];
            #pragma unroll
            for (int mt = 0; mt < 2; ++mt)
                #pragma unroll
                for (int nt = 0; nt < 2; ++nt)
                    acc[mt][nt] = __builtin_amdgcn_mfma_f32_16x16x32_bf16(
                        bv[nt], av[mt][ks], acc[mt][nt], 0, 0, 0);
        }

        // ---- tanh + pack to fc2-A-frag layout in hs ----
        const int q2base = q >> 1, slot = q & 1;
        #pragma unroll
        for (int mt = 0; mt < 2; ++mt) {
            const int Rl = wm * 2 + mt;              // local row-tile 0..3
            #pragma unroll
            for (int nt = 0; nt < 2; ++nt) {
                float tv[4];
                #pragma unroll
                for (int r = 0; r < 4; ++r)
                    tv[r] = 1.f - 2.f / (__expf(2.f * acc[mt][nt][r]) + 1.f);
                const int q2 = nt * 2 + q2base;      // (CTl&1)*2 + q2base
                const uint p0 = packbf2(tv[0], tv[1]);
                const uint p1 = packbf2(tv[2], tv[3]);
                *(uint2*)(hsb + (((Rl * 4 + wn) * 64 + q2 * 16 + m) * 16 + slot * 8))
                    = make_uint2(p0, p1);
            }
        }

        // mid-chunk barrier: LDS writes visible, but vmcnt NOT drained
        asm volatile("s_waitcnt lgkmcnt(0)" ::: "memory");
        __builtin_amdgcn_sched_barrier(0);
        __builtin_amdgcn_s_barrier();

        // ---- fc2 partial: wave's k-slice = [ch*128 + wn*32, +32) ----
        {
            short8 a2[4];
            #pragma unroll
            for (int Rl = 0; Rl < 4; ++Rl)
                a2[Rl] = *(const short8*)(hsb + ((Rl * 4 + wn) * 64 + lane) * 16);
            #pragma unroll
            for (int Rl = 0; Rl < 4; ++Rl)
                #pragma unroll
                for (int Otp = 0; Otp < 2; ++Otp)
                    acc2[Rl][Otp] = __builtin_amdgcn_mfma_f32_16x16x32_bf16(
                        a2[Rl], b2[Otp], acc2[Rl][Otp], 0, 0, 0);
        }

        // end-of-chunk: drains vmcnt(0) (prefetch landed) + hs reads done
        __syncthreads();
    }

    // ---- epilogue: spill k-partials, reduce, bias, softmax ----
    // (Bs region is dead; partf[4][64][64] aliases it)
    #pragma unroll
    for (int Rl = 0; Rl < 4; ++Rl)
        #pragma unroll
        for (int Otp = 0; Otp < 2; ++Otp)
            #pragma unroll
            for (int r = 0; r < 4; ++r)
                partf[(wn * 64 + Rl * 16 + q * 4 + r) * 64
                      + wm * 32 + Otp * 16 + m] = acc2[Rl][Otp][r];
    __syncthreads();

    #pragma unroll
    for (int t = 0; t < 8; ++t) {
        int idx = t * 512 + tid;
        int row = idx >> 6, col = idx & 63;
        float lg = partf[row * 64 + col] + partf[(64 + row) * 64 + col]
                 + partf[(128 + row) * 64 + col] + partf[(192 + row) * 64 + col];
        partf[row * 64 + col] = (col < 50) ? lg + fc2_b[col] : -1e30f;
    }
    __syncthreads();

    #pragma unroll
    for (int rr = 0; rr < 8; ++rr) {
        const int row = wv * 8 + rr;
        float v = partf[row * 64 + lane];
        float mx = v;
        #pragma unroll
        for (int off = 32; off > 0; off >>= 1) mx = fmaxf(mx, __shfl_xor(mx, off));
        float e = __expf(v - mx);
        float s = e;
        #pragma unroll
        for (int off = 32; off > 0; off >>= 1) s += __shfl_xor(s, off);
        if (lane < 50)
            out[(size_t)(m0 + row) * 50 + lane] = e / s;
    }
}

// ---------------------------------------------------------------------------
extern "C" void kernel_launch(void* const* d_in, const int* in_sizes, int n_in,
                              void* d_out, int out_size, void* d_ws, size_t ws_size,
                              hipStream_t stream) {
    const int*   x        = (const int*)  d_in[0];
    const int*   wci      = (const int*)  d_in[1];
    const float* word_emb = (const float*)d_in[2];
    const float* char_emb = (const float*)d_in[3];
    const float* conv_w   = (const float*)d_in[4];
    const float* conv_b   = (const float*)d_in[5];
    const float* fc1_w    = (const float*)d_in[6];
    const float* fc1_b    = (const float*)d_in[7];
    const float* fc2_w    = (const float*)d_in[8];
    const float* fc2_b    = (const float*)d_in[9];
    float* out = (float*)d_out;

    char* ws = (char*)d_ws;
    __hip_bfloat16* ha  = (__hip_bfloat16*)ws;                        // 8 MB
    short* wbf  = (short*)(ws + ((size_t)8  << 20));                  // 2 MB
    short* w2bf = (short*)(ws + ((size_t)10 << 20));                  // 0.5 MB
    float* gtp  = (float*)(ws + ((size_t)11 << 20));                  // 78 KB

    wbf_kernel<<<4096, 256, 0, stream>>>(fc1_w, fc1_b, wbf);
    w2bf_kernel<<<1024, 256, 0, stream>>>(fc2_w, w2bf);
    gt_kernel<<<75, 256, 0, stream>>>(char_emb, conv_w, gtp);
    haPad_kernel<<<384, 256, 0, stream>>>(ha);
    conv_kernel<<<2560, 512, 0, stream>>>(x, wci, word_emb, conv_b, gtp, ha);
    fused_kernel<<<256, 512, 0, stream>>>(ha, wbf, w2bf, fc2_b, out);
}